// Round 15
// baseline (266.618 us; speedup 1.0000x reference)
//
#include <hip/hip_runtime.h>
#include <hip/hip_bf16.h>
#include <stdint.h>
#include <string.h>

#define NN 40000
#define NE 640000
#define D  128
#define NL 4
#define EPSV 1e-6f
#define CSRP 1280000   // padded csr capacity: NE + 16*NN worst case
#define TBYTES 10240256u  // (NN+1) * 256 bytes per t buffer

typedef __attribute__((ext_vector_type(8))) short          s16x8;
typedef __attribute__((ext_vector_type(8))) unsigned short u16x8;
typedef __attribute__((ext_vector_type(4))) unsigned short u16x4;
typedef __attribute__((ext_vector_type(2))) unsigned short u16x2;
typedef __attribute__((ext_vector_type(4))) float          f32x4;
typedef __attribute__((ext_vector_type(4))) uint32_t       u32x4;

static __device__ __forceinline__ unsigned short f2b_bits(float f) {
  uint32_t u = __float_as_uint(f);
  uint32_t r = (u + 0x7fffu + ((u >> 16) & 1u)) >> 16;   // RNE
  return (unsigned short)r;
}
static __device__ __forceinline__ float b2f(unsigned short b) {
  return __uint_as_float((uint32_t)b << 16);
}
// packed bf16 max in integer domain (valid: t>=0 so bit order == float order)
static __device__ __forceinline__ uint32_t pk32(uint32_t a, uint32_t b) {
  u16x2 x = __builtin_bit_cast(u16x2, a);
  u16x2 y = __builtin_bit_cast(u16x2, b);
  return __builtin_bit_cast(uint32_t, __builtin_elementwise_max(x, y));
}

// ---- merged prep: weights fp32->bf16, csr sentinel fill, t sentinels, deg count ---
__global__ void k_prep(const float* __restrict__ Wc, const float* __restrict__ Wh,
                       unsigned short* __restrict__ wcb, unsigned short* __restrict__ whb,
                       int* __restrict__ csr, unsigned short* __restrict__ s0,
                       unsigned short* __restrict__ s1,
                       const int* __restrict__ e, int* __restrict__ deg) {
  int i = blockIdx.x * 256 + threadIdx.x;
  if (i < NL * D * D) {
    wcb[i] = f2b_bits(Wc[i]);
    whb[i] = f2b_bits(Wh[i]);
  }
  if (i < CSRP) csr[i] = NN;
  if (i < D) { s0[i] = 0; s1[i] = 0; }
  if (i < NE) atomicAdd(&deg[e[2 * i + 1]], 1);
}

// ---------------- CSR build (scan-free, 16-padded chunks, min 16) ----------------
__global__ void k_alloc(const int* __restrict__ deg, int* __restrict__ total,
                        int* __restrict__ rs) {
  int i = blockIdx.x * 256 + threadIdx.x;
  if (i < NN) {
    int d = (deg[i] + 15) & ~15;
    if (d < 16) d = 16;
    rs[i] = atomicAdd(total, d);
  }
}

__global__ void k_fill(const int* __restrict__ e, const int* __restrict__ rs,
                       int* __restrict__ cursor, int* __restrict__ csr) {
  int i = blockIdx.x * 256 + threadIdx.x;
  if (i < NE) {
    int s = e[2 * i + 0];
    int d = e[2 * i + 1];
    int p = atomicAdd(&cursor[d], 1);
    csr[rs[d] + p] = s;
  }
}

// ---------------- layer-0 edge GEMM: t = relu(x @ Wc^T + bc) -> bf16 ----------------
__global__ __launch_bounds__(256) void k_gemm0(
    const float* __restrict__ hin,
    const unsigned short* __restrict__ Wb,
    const float* __restrict__ bias,
    unsigned short* __restrict__ tout) {
  __shared__ float lds[4][16][D];
  int wave = threadIdx.x >> 6, lane = threadIdx.x & 63;
  int rowbase = (blockIdx.x * 4 + wave) * 16;
  int c15 = lane & 15, grp = lane >> 4;

  s16x8 a[4];
  {
    const float* hp = hin + (size_t)(rowbase + c15) * D;
#pragma unroll
    for (int ks = 0; ks < 4; ++ks) {
      int k0 = ks * 32 + grp * 8;
      f32x4 x0 = *(const f32x4*)(hp + k0);
      f32x4 x1 = *(const f32x4*)(hp + k0 + 4);
      u16x8 av;
      av[0] = f2b_bits(x0[0]); av[1] = f2b_bits(x0[1]);
      av[2] = f2b_bits(x0[2]); av[3] = f2b_bits(x0[3]);
      av[4] = f2b_bits(x1[0]); av[5] = f2b_bits(x1[1]);
      av[6] = f2b_bits(x1[2]); av[7] = f2b_bits(x1[3]);
      a[ks] = __builtin_bit_cast(s16x8, av);
    }
  }

  f32x4 acc[8];
#pragma unroll
  for (int ct = 0; ct < 8; ++ct) { f32x4 z = {0.f, 0.f, 0.f, 0.f}; acc[ct] = z; }
#pragma unroll
  for (int ct = 0; ct < 8; ++ct) {
    const unsigned short* wp = Wb + (size_t)(ct * 16 + c15) * D;
#pragma unroll
    for (int ks = 0; ks < 4; ++ks) {
      s16x8 b = *(const s16x8*)(wp + ks * 32 + grp * 8);
      acc[ct] = __builtin_amdgcn_mfma_f32_16x16x32_bf16(a[ks], b, acc[ct], 0, 0, 0);
    }
  }
#pragma unroll
  for (int ct = 0; ct < 8; ++ct) {
    int col = ct * 16 + c15;
    float bv = bias[col];
#pragma unroll
    for (int r = 0; r < 4; ++r)
      lds[wave][grp * 4 + r][col] = fmaxf(acc[ct][r] + bv, 0.f);
  }
  __syncthreads();
#pragma unroll
  for (int it = 0; it < 4; ++it) {
    int idx = it * 512 + lane * 8;
    int r = idx >> 7, c = idx & 127;
    const float* lp = &lds[wave][r][c];
    f32x4 v0 = *(const f32x4*)lp;
    f32x4 v1 = *(const f32x4*)(lp + 4);
    u16x8 ov;
    ov[0] = f2b_bits(v0[0]); ov[1] = f2b_bits(v0[1]);
    ov[2] = f2b_bits(v0[2]); ov[3] = f2b_bits(v0[3]);
    ov[4] = f2b_bits(v1[0]); ov[5] = f2b_bits(v1[1]);
    ov[6] = f2b_bits(v1[2]); ov[7] = f2b_bits(v1[3]);
    *(u16x8*)(tout + (size_t)(rowbase + r) * D + c) = ov;
  }
}

// ---------------- full layer, block-cooperative (block = 8 waves, 16 nodes) ----------
// phase1: gather; t-row loads via buffer_load sc0 (agent scope: bypass CU-L1 miss
//         path, keep L2 allocation). 16-padded sentinel CSR; packed u16 max.
// phase2: MLP GEMM, 1 ct-tile per wave; residual+rmsnorm -> hout (+ LDS)
// phase3: next-layer edge GEMM, 1 ct-tile per wave -> bf16 t'
template <int WRITE_T>
__global__ __launch_bounds__(512) void k_layer(
    const float* __restrict__ hin,
    const uint32_t* __restrict__ tp,       // bf16x2 rows [NN+1][64] (256B rows; row NN = 0)
    const int* __restrict__ rs, const int* __restrict__ deg, const int* __restrict__ csr,
    const float* __restrict__ gcv, const float* __restrict__ bgcv,
    const unsigned short* __restrict__ Whb, const float* __restrict__ bhv,
    const float* __restrict__ ghv, const float* __restrict__ bghv,
    const unsigned short* __restrict__ Wcb, const float* __restrict__ bcv,
    float* __restrict__ hout, unsigned short* __restrict__ tout) {
  __shared__ float u[16][132];
  int tid = threadIdx.x;
  int wave = tid >> 6, lane = tid & 63;
  int q = lane & 15, g = lane >> 4;
  int rowbase = blockIdx.x * 16;

  // ---- phase 1: gather-max + residual + rmsnorm (2 nodes per wave) ----
  {
    int waveu = __builtin_amdgcn_readfirstlane(wave);
    int na = rowbase + waveu * 2;          // uniform
    int r0a = rs[na], r0b = rs[na + 1];    // uniform-address -> SGPR
    int dpa = (deg[na] + 15) & ~15; if (dpa < 16) dpa = 16;
    int dpb = (deg[na + 1] + 15) & ~15; if (dpb < 16) dpb = 16;
    uint32_t loff = (uint32_t)lane * 4u;   // lane's dword of the 256B row (dims 2l,2l+1)
    int d0 = lane * 2;
    int nla = waveu * 2;

    // SRSRC for t buffer (stride 0, raw): num_records = bytes, bounds-checked
    u32x4 srsrc;
    {
      uint64_t ad = (uint64_t)tp;
      srsrc.x = (uint32_t)ad;
      srsrc.y = (uint32_t)(ad >> 32);
      srsrc.z = TBYTES;
      srsrc.w = 0x00020000u;
    }

    // independent loads issued early
    float2 hva  = *(const float2*)(hin + (size_t)na * D + d0);
    float2 hvb  = *(const float2*)(hin + (size_t)(na + 1) * D + d0);
    float2 gc2  = *(const float2*)(gcv + d0);
    float2 bgc2 = *(const float2*)(bgcv + d0);

    const int* __restrict__ csa = csr + r0a;
    const int* __restrict__ csb = csr + r0b;

#define BL(dst, S) asm volatile("buffer_load_dword %0, %1, %2, 0 offen sc0" \
      : "=v"(dst) : "v"((((uint32_t)(S)) << 8) + loff), "s"(srsrc))

    uint32_t a0, a1, a2, a3, b0, b1, b2, b3;
    uint32_t xa[16], yb[16];
    {
      // first chunk: 32 unconditional back-to-back loads (dp >= 16 always)
#pragma unroll
      for (int j = 0; j < 16; ++j) BL(xa[j], csa[j]);
#pragma unroll
      for (int j = 0; j < 16; ++j) BL(yb[j], csb[j]);
      asm volatile("s_waitcnt vmcnt(0)" ::: "memory");
      __builtin_amdgcn_sched_barrier(0);
      a0 = pk32(pk32(xa[0], xa[4]), pk32(xa[8],  xa[12]));
      a1 = pk32(pk32(xa[1], xa[5]), pk32(xa[9],  xa[13]));
      a2 = pk32(pk32(xa[2], xa[6]), pk32(xa[10], xa[14]));
      a3 = pk32(pk32(xa[3], xa[7]), pk32(xa[11], xa[15]));
      b0 = pk32(pk32(yb[0], yb[4]), pk32(yb[8],  yb[12]));
      b1 = pk32(pk32(yb[1], yb[5]), pk32(yb[9],  yb[13]));
      b2 = pk32(pk32(yb[2], yb[6]), pk32(yb[10], yb[14]));
      b3 = pk32(pk32(yb[3], yb[7]), pk32(yb[11], yb[15]));
    }
    int rmax = dpa > dpb ? dpa : dpb;
    for (int i = 16; i < rmax; i += 16) {
      bool da = i < dpa, db = i < dpb;
      if (da) {
#pragma unroll
        for (int j = 0; j < 16; ++j) BL(xa[j], csa[i + j]);
      }
      if (db) {
#pragma unroll
        for (int j = 0; j < 16; ++j) BL(yb[j], csb[i + j]);
      }
      asm volatile("s_waitcnt vmcnt(0)" ::: "memory");
      __builtin_amdgcn_sched_barrier(0);
      if (da) {
        a0 = pk32(a0, pk32(pk32(xa[0], xa[4]), pk32(xa[8],  xa[12])));
        a1 = pk32(a1, pk32(pk32(xa[1], xa[5]), pk32(xa[9],  xa[13])));
        a2 = pk32(a2, pk32(pk32(xa[2], xa[6]), pk32(xa[10], xa[14])));
        a3 = pk32(a3, pk32(pk32(xa[3], xa[7]), pk32(xa[11], xa[15])));
      }
      if (db) {
        b0 = pk32(b0, pk32(pk32(yb[0], yb[4]), pk32(yb[8],  yb[12])));
        b1 = pk32(b1, pk32(pk32(yb[1], yb[5]), pk32(yb[9],  yb[13])));
        b2 = pk32(b2, pk32(pk32(yb[2], yb[6]), pk32(yb[10], yb[14])));
        b3 = pk32(b3, pk32(pk32(yb[3], yb[7]), pk32(yb[11], yb[15])));
      }
    }
#undef BL
    uint32_t am = pk32(pk32(a0, a1), pk32(a2, a3));
    uint32_t bm = pk32(pk32(b0, b1), pk32(b2, b3));

    float ua0 = hva.x + b2f((unsigned short)(am & 0xffffu));
    float ua1 = hva.y + b2f((unsigned short)(am >> 16));
    float ub0 = hvb.x + b2f((unsigned short)(bm & 0xffffu));
    float ub1 = hvb.y + b2f((unsigned short)(bm >> 16));
    float ssa = ua0 * ua0 + ua1 * ua1;
    float ssb = ub0 * ub0 + ub1 * ub1;
#pragma unroll
    for (int off = 32; off; off >>= 1) {
      ssa += __shfl_xor(ssa, off);
      ssb += __shfl_xor(ssb, off);
    }
    float rfa = rsqrtf(ssa * (1.f / D) + EPSV);
    float rfb = rsqrtf(ssb * (1.f / D) + EPSV);
    u[nla][d0]         = ua0 * rfa * gc2.x + bgc2.x;
    u[nla][d0 + 1]     = ua1 * rfa * gc2.y + bgc2.y;
    u[nla + 1][d0]     = ub0 * rfb * gc2.x + bgc2.x;
    u[nla + 1][d0 + 1] = ub1 * rfb * gc2.y + bgc2.y;
  }
  __syncthreads();

  // ---- phase 2: MLP GEMM, wave handles ct-tile = wave ----
  const char* whB = (const char*)Whb;
  uint32_t wrow = (uint32_t)(wave * 16 + q) * (D * 2);
  s16x8 a[4];
#pragma unroll
  for (int ks = 0; ks < 4; ++ks) {
    int k0 = ks * 32 + g * 8;
    f32x4 x0 = *(const f32x4*)&u[q][k0];
    f32x4 x1 = *(const f32x4*)&u[q][k0 + 4];
    u16x8 av;
    av[0] = f2b_bits(x0[0]); av[1] = f2b_bits(x0[1]);
    av[2] = f2b_bits(x0[2]); av[3] = f2b_bits(x0[3]);
    av[4] = f2b_bits(x1[0]); av[5] = f2b_bits(x1[1]);
    av[6] = f2b_bits(x1[2]); av[7] = f2b_bits(x1[3]);
    a[ks] = __builtin_bit_cast(s16x8, av);
  }
  f32x4 acc = {0.f, 0.f, 0.f, 0.f};
#pragma unroll
  for (int ks = 0; ks < 4; ++ks) {
    s16x8 b = *(const s16x8*)(whB + wrow + (uint32_t)(ks * 32 + g * 8) * 2);
    acc = __builtin_amdgcn_mfma_f32_16x16x32_bf16(a[ks], b, acc, 0, 0, 0);
  }
  __syncthreads();                         // all A-frag reads done
  {
    int col = wave * 16 + q;
    float bv = bhv[col];
#pragma unroll
    for (int r = 0; r < 4; ++r)
      u[g * 4 + r][col] += fmaxf(acc[r] + bv, 0.f);
  }
  __syncthreads();
  // rmsnorm: wave handles rows {2*wave, 2*wave+1}; write h2 to global + LDS
  {
    int d0 = lane * 2;
    float2 gh2  = *(const float2*)(ghv + d0);
    float2 bgh2 = *(const float2*)(bghv + d0);
#pragma unroll
    for (int j = 0; j < 2; ++j) {
      int r = wave * 2 + j;
      float u0 = u[r][d0], u1 = u[r][d0 + 1];
      float ss = u0 * u0 + u1 * u1;
#pragma unroll
      for (int off2 = 32; off2; off2 >>= 1) ss += __shfl_xor(ss, off2);
      float rf = rsqrtf(ss * (1.f / D) + EPSV);
      float o0 = u0 * rf * gh2.x + bgh2.x;
      float o1 = u1 * rf * gh2.y + bgh2.y;
      u[r][d0]     = o0;
      u[r][d0 + 1] = o1;
      float2 o; o.x = o0; o.y = o1;
      *(float2*)(hout + (size_t)(rowbase + r) * D + d0) = o;
    }
  }

  if (WRITE_T) {
    __syncthreads();
    // phase 3: next-layer edge GEMM from LDS h2
    const char* wcB = (const char*)Wcb;
    s16x8 a2[4];
#pragma unroll
    for (int ks = 0; ks < 4; ++ks) {
      int k0 = ks * 32 + g * 8;
      f32x4 x0 = *(const f32x4*)&u[q][k0];
      f32x4 x1 = *(const f32x4*)&u[q][k0 + 4];
      u16x8 av;
      av[0] = f2b_bits(x0[0]); av[1] = f2b_bits(x0[1]);
      av[2] = f2b_bits(x0[2]); av[3] = f2b_bits(x0[3]);
      av[4] = f2b_bits(x1[0]); av[5] = f2b_bits(x1[1]);
      av[6] = f2b_bits(x1[2]); av[7] = f2b_bits(x1[3]);
      a2[ks] = __builtin_bit_cast(s16x8, av);
    }
    f32x4 acc2 = {0.f, 0.f, 0.f, 0.f};
#pragma unroll
    for (int ks = 0; ks < 4; ++ks) {
      s16x8 b = *(const s16x8*)(wcB + wrow + (uint32_t)(ks * 32 + g * 8) * 2);
      acc2 = __builtin_amdgcn_mfma_f32_16x16x32_bf16(a2[ks], b, acc2, 0, 0, 0);
    }
    __syncthreads();
    {
      int col = wave * 16 + q;
      float bv = bcv[col];
#pragma unroll
      for (int r = 0; r < 4; ++r)
        u[g * 4 + r][col] = fmaxf(acc2[r] + bv, 0.f);
    }
    __syncthreads();
    // coalesced bf16 store: thread -> row tid>>5, cols (tid&31)*4..+3
    {
      int r = tid >> 5, c = (tid & 31) * 4;
      f32x4 v = *(const f32x4*)&u[r][c];
      u16x4 ov;
      ov[0] = f2b_bits(v[0]); ov[1] = f2b_bits(v[1]);
      ov[2] = f2b_bits(v[2]); ov[3] = f2b_bits(v[3]);
      *(u16x4*)(tout + (size_t)(rowbase + r) * D + c) = ov;
    }
  }
}

// ---------------- launch ----------------
extern "C" void kernel_launch(void* const* d_in, const int* in_sizes, int n_in,
                              void* d_out, int out_size, void* d_ws, size_t ws_size,
                              hipStream_t stream) {
  (void)in_sizes; (void)n_in; (void)out_size; (void)ws_size;
  const float* x   = (const float*)d_in[0];
  const int*   e   = (const int*)d_in[1];
  const float* Wc  = (const float*)d_in[2];
  const float* bc  = (const float*)d_in[3];
  const float* gc  = (const float*)d_in[4];
  const float* bgc = (const float*)d_in[5];
  const float* Wh  = (const float*)d_in[6];
  const float* bh  = (const float*)d_in[7];
  const float* gh  = (const float*)d_in[8];
  const float* bgh = (const float*)d_in[9];
  float* out = (float*)d_out;

  // t buffers have NN+1 rows: row NN is the zero sentinel for csr pads
  char* base = (char*)d_ws;
  unsigned short* t0  = (unsigned short*)(base + 0);          // 10,240,256 (+pad)
  unsigned short* t1  = (unsigned short*)(base + 10240512);   // 10,240,256 (+pad)
  float*          hA  = (float*)(base + 20481024);            // 20,480,000
  unsigned short* wcb = (unsigned short*)(base + 40961024);   //    131,072
  unsigned short* whb = (unsigned short*)(base + 41092096);   //    131,072
  int*            deg = (int*)(base + 41223168);              //    160,000
  int*            cur = (int*)(base + 41383168);              //    160,000
  int*            tot = (int*)(base + 41543168);              //         64
  int*            rs  = (int*)(base + 41543232);              //    160,000
  int*            csr = (int*)(base + 41703232);              //  5,120,000

  hipMemsetAsync(deg, 0, 2 * 160000 + 64, stream);   // deg | cur | tot (before k_prep!)
  k_prep<<<5000, 256, 0, stream>>>(Wc, Wh, wcb, whb, csr,
                                   t0 + (size_t)NN * D, t1 + (size_t)NN * D, e, deg);
  k_alloc<<<157, 256, 0, stream>>>(deg, tot, rs);
  k_fill<<<2500, 256, 0, stream>>>(e, rs, cur, csr);

  // layer-0 t on x
  k_gemm0<<<625, 256, 0, stream>>>(x, wcb, bc, t0);

  unsigned short* tbuf[2] = {t0, t1};
  for (int l = 0; l < NL; ++l) {
    const float* hin = (l == 0) ? x : hA;
    const uint32_t* tin = (const uint32_t*)tbuf[l & 1];
    if (l < NL - 1) {
      k_layer<1><<<2500, 512, 0, stream>>>(
          hin, tin, rs, deg, csr,
          gc + l * D, bgc + l * D,
          whb + (size_t)l * D * D, bh + l * D, gh + l * D, bgh + l * D,
          wcb + (size_t)(l + 1) * D * D, bc + (l + 1) * D,
          hA, tbuf[(l + 1) & 1]);
    } else {
      k_layer<0><<<2500, 512, 0, stream>>>(
          hin, tin, rs, deg, csr,
          gc + l * D, bgc + l * D,
          whb + (size_t)l * D * D, bh + l * D, gh + l * D, bgh + l * D,
          nullptr, nullptr,
          out, nullptr);
    }
  }
}

// Round 16
// 255.767 us; speedup vs baseline: 1.0424x; 1.0424x over previous
//
#include <hip/hip_runtime.h>
#include <hip/hip_bf16.h>
#include <stdint.h>
#include <string.h>

#define NN 40000
#define NE 640000
#define D  128
#define NL 4
#define EPSV 1e-6f
#define CSRP 1280000   // padded csr capacity: NE + 16*NN worst case

typedef __attribute__((ext_vector_type(8))) short          s16x8;
typedef __attribute__((ext_vector_type(8))) unsigned short u16x8;
typedef __attribute__((ext_vector_type(4))) unsigned short u16x4;
typedef __attribute__((ext_vector_type(2))) unsigned short u16x2;
typedef __attribute__((ext_vector_type(4))) float          f32x4;

static __device__ __forceinline__ unsigned short f2b_bits(float f) {
  uint32_t u = __float_as_uint(f);
  uint32_t r = (u + 0x7fffu + ((u >> 16) & 1u)) >> 16;   // RNE
  return (unsigned short)r;
}
static __device__ __forceinline__ float b2f(unsigned short b) {
  return __uint_as_float((uint32_t)b << 16);
}
// packed bf16 max in integer domain (valid: t>=0 so bit order == float order)
static __device__ __forceinline__ uint32_t pk32(uint32_t a, uint32_t b) {
  u16x2 x = __builtin_bit_cast(u16x2, a);
  u16x2 y = __builtin_bit_cast(u16x2, b);
  return __builtin_bit_cast(uint32_t, __builtin_elementwise_max(x, y));
}

// ---- merged prep: weights fp32->bf16, csr sentinel fill, t sentinels, deg count ---
// (memset of deg runs before this kernel; atomics within one kernel need no order)
__global__ void k_prep(const float* __restrict__ Wc, const float* __restrict__ Wh,
                       unsigned short* __restrict__ wcb, unsigned short* __restrict__ whb,
                       int* __restrict__ csr, unsigned short* __restrict__ s0,
                       unsigned short* __restrict__ s1,
                       const int* __restrict__ e, int* __restrict__ deg) {
  int i = blockIdx.x * 256 + threadIdx.x;
  if (i < NL * D * D) {
    wcb[i] = f2b_bits(Wc[i]);
    whb[i] = f2b_bits(Wh[i]);
  }
  if (i < CSRP) csr[i] = NN;
  if (i < D) { s0[i] = 0; s1[i] = 0; }
  if (i < NE) atomicAdd(&deg[e[2 * i + 1]], 1);
}

// ---------------- CSR build (scan-free, 16-padded chunks, min 16) ----------------
__global__ void k_alloc(const int* __restrict__ deg, int* __restrict__ total,
                        int* __restrict__ rs) {
  int i = blockIdx.x * 256 + threadIdx.x;
  if (i < NN) {
    int d = (deg[i] + 15) & ~15;
    if (d < 16) d = 16;
    rs[i] = atomicAdd(total, d);
  }
}

__global__ void k_fill(const int* __restrict__ e, const int* __restrict__ rs,
                       int* __restrict__ cursor, int* __restrict__ csr) {
  int i = blockIdx.x * 256 + threadIdx.x;
  if (i < NE) {
    int s = e[2 * i + 0];
    int d = e[2 * i + 1];
    int p = atomicAdd(&cursor[d], 1);
    csr[rs[d] + p] = s;
  }
}

// ---------------- layer-0 edge GEMM: t = relu(x @ Wc^T + bc) -> bf16 ----------------
__global__ __launch_bounds__(256) void k_gemm0(
    const float* __restrict__ hin,
    const unsigned short* __restrict__ Wb,
    const float* __restrict__ bias,
    unsigned short* __restrict__ tout) {
  __shared__ float lds[4][16][D];
  int wave = threadIdx.x >> 6, lane = threadIdx.x & 63;
  int rowbase = (blockIdx.x * 4 + wave) * 16;
  int c15 = lane & 15, grp = lane >> 4;

  s16x8 a[4];
  {
    const float* hp = hin + (size_t)(rowbase + c15) * D;
#pragma unroll
    for (int ks = 0; ks < 4; ++ks) {
      int k0 = ks * 32 + grp * 8;
      f32x4 x0 = *(const f32x4*)(hp + k0);
      f32x4 x1 = *(const f32x4*)(hp + k0 + 4);
      u16x8 av;
      av[0] = f2b_bits(x0[0]); av[1] = f2b_bits(x0[1]);
      av[2] = f2b_bits(x0[2]); av[3] = f2b_bits(x0[3]);
      av[4] = f2b_bits(x1[0]); av[5] = f2b_bits(x1[1]);
      av[6] = f2b_bits(x1[2]); av[7] = f2b_bits(x1[3]);
      a[ks] = __builtin_bit_cast(s16x8, av);
    }
  }

  f32x4 acc[8];
#pragma unroll
  for (int ct = 0; ct < 8; ++ct) { f32x4 z = {0.f, 0.f, 0.f, 0.f}; acc[ct] = z; }
#pragma unroll
  for (int ct = 0; ct < 8; ++ct) {
    const unsigned short* wp = Wb + (size_t)(ct * 16 + c15) * D;
#pragma unroll
    for (int ks = 0; ks < 4; ++ks) {
      s16x8 b = *(const s16x8*)(wp + ks * 32 + grp * 8);
      acc[ct] = __builtin_amdgcn_mfma_f32_16x16x32_bf16(a[ks], b, acc[ct], 0, 0, 0);
    }
  }
#pragma unroll
  for (int ct = 0; ct < 8; ++ct) {
    int col = ct * 16 + c15;
    float bv = bias[col];
#pragma unroll
    for (int r = 0; r < 4; ++r)
      lds[wave][grp * 4 + r][col] = fmaxf(acc[ct][r] + bv, 0.f);
  }
  __syncthreads();
#pragma unroll
  for (int it = 0; it < 4; ++it) {
    int idx = it * 512 + lane * 8;
    int r = idx >> 7, c = idx & 127;
    const float* lp = &lds[wave][r][c];
    f32x4 v0 = *(const f32x4*)lp;
    f32x4 v1 = *(const f32x4*)(lp + 4);
    u16x8 ov;
    ov[0] = f2b_bits(v0[0]); ov[1] = f2b_bits(v0[1]);
    ov[2] = f2b_bits(v0[2]); ov[3] = f2b_bits(v0[3]);
    ov[4] = f2b_bits(v1[0]); ov[5] = f2b_bits(v1[1]);
    ov[6] = f2b_bits(v1[2]); ov[7] = f2b_bits(v1[3]);
    *(u16x8*)(tout + (size_t)(rowbase + r) * D + c) = ov;
  }
}

// ---------------- full layer, block-cooperative (block = 8 waves, 16 nodes) ----------
// phase1: gather with 32 unconditional back-to-back row loads (16/node-stream),
//         16-padded sentinel CSR (no clamps/tails); packed u16 max; dword/lane.
// phase2: MLP GEMM, 1 ct-tile per wave; residual+rmsnorm -> hout (+ LDS)
// phase3: next-layer edge GEMM, 1 ct-tile per wave -> bf16 t'
template <int WRITE_T>
__global__ __launch_bounds__(512) void k_layer(
    const float* __restrict__ hin,
    const uint32_t* __restrict__ tp,       // bf16x2 rows [NN+1][64] (256B rows; row NN = 0)
    const int* __restrict__ rs, const int* __restrict__ deg, const int* __restrict__ csr,
    const float* __restrict__ gcv, const float* __restrict__ bgcv,
    const unsigned short* __restrict__ Whb, const float* __restrict__ bhv,
    const float* __restrict__ ghv, const float* __restrict__ bghv,
    const unsigned short* __restrict__ Wcb, const float* __restrict__ bcv,
    float* __restrict__ hout, unsigned short* __restrict__ tout) {
  __shared__ float u[16][132];
  int tid = threadIdx.x;
  int wave = tid >> 6, lane = tid & 63;
  int q = lane & 15, g = lane >> 4;
  int rowbase = blockIdx.x * 16;

  // ---- phase 1: gather-max + residual + rmsnorm (2 nodes per wave) ----
  {
    int waveu = __builtin_amdgcn_readfirstlane(wave);
    int na = rowbase + waveu * 2;          // uniform
    int r0a = rs[na], r0b = rs[na + 1];    // uniform-address -> SGPR
    int dpa = (deg[na] + 15) & ~15; if (dpa < 16) dpa = 16;
    int dpb = (deg[na + 1] + 15) & ~15; if (dpb < 16) dpb = 16;
    const char* __restrict__ tb = (const char*)tp;
    uint32_t loff = (uint32_t)lane * 4u;   // lane's dword of the 256B row (dims 2l,2l+1)
    int d0 = lane * 2;
    int nla = waveu * 2;

    // independent loads issued early
    float2 hva  = *(const float2*)(hin + (size_t)na * D + d0);
    float2 hvb  = *(const float2*)(hin + (size_t)(na + 1) * D + d0);
    float2 gc2  = *(const float2*)(gcv + d0);
    float2 bgc2 = *(const float2*)(bgcv + d0);

    const int* __restrict__ csa = csr + r0a;
    const int* __restrict__ csb = csr + r0b;

#define TL(S) (*(const uint32_t*)(tb + ((((uint32_t)(S)) << 8) + loff)))
    uint32_t a0, a1, a2, a3, b0, b1, b2, b3;
    {
      // first chunk: 32 unconditional back-to-back loads (dp >= 16 always)
      uint32_t x0  = TL(csa[0]),  x1  = TL(csa[1]),  x2  = TL(csa[2]),  x3  = TL(csa[3]);
      uint32_t x4  = TL(csa[4]),  x5  = TL(csa[5]),  x6  = TL(csa[6]),  x7  = TL(csa[7]);
      uint32_t x8  = TL(csa[8]),  x9  = TL(csa[9]),  x10 = TL(csa[10]), x11 = TL(csa[11]);
      uint32_t x12 = TL(csa[12]), x13 = TL(csa[13]), x14 = TL(csa[14]), x15 = TL(csa[15]);
      uint32_t y0  = TL(csb[0]),  y1  = TL(csb[1]),  y2  = TL(csb[2]),  y3  = TL(csb[3]);
      uint32_t y4  = TL(csb[4]),  y5  = TL(csb[5]),  y6  = TL(csb[6]),  y7  = TL(csb[7]);
      uint32_t y8  = TL(csb[8]),  y9  = TL(csb[9]),  y10 = TL(csb[10]), y11 = TL(csb[11]);
      uint32_t y12 = TL(csb[12]), y13 = TL(csb[13]), y14 = TL(csb[14]), y15 = TL(csb[15]);
      a0 = pk32(x0, x4);  a1 = pk32(x1, x5);  a2 = pk32(x2, x6);  a3 = pk32(x3, x7);
      a0 = pk32(a0, x8);  a1 = pk32(a1, x9);  a2 = pk32(a2, x10); a3 = pk32(a3, x11);
      a0 = pk32(a0, x12); a1 = pk32(a1, x13); a2 = pk32(a2, x14); a3 = pk32(a3, x15);
      b0 = pk32(y0, y4);  b1 = pk32(y1, y5);  b2 = pk32(y2, y6);  b3 = pk32(y3, y7);
      b0 = pk32(b0, y8);  b1 = pk32(b1, y9);  b2 = pk32(b2, y10); b3 = pk32(b3, y11);
      b0 = pk32(b0, y12); b1 = pk32(b1, y13); b2 = pk32(b2, y14); b3 = pk32(b3, y15);
    }
    int rmax = dpa > dpb ? dpa : dpb;
    for (int i = 16; i < rmax; i += 16) {
      if (i < dpa) {
        uint32_t x0  = TL(csa[i+0]),  x1  = TL(csa[i+1]),  x2  = TL(csa[i+2]),  x3  = TL(csa[i+3]);
        uint32_t x4  = TL(csa[i+4]),  x5  = TL(csa[i+5]),  x6  = TL(csa[i+6]),  x7  = TL(csa[i+7]);
        uint32_t x8  = TL(csa[i+8]),  x9  = TL(csa[i+9]),  x10 = TL(csa[i+10]), x11 = TL(csa[i+11]);
        uint32_t x12 = TL(csa[i+12]), x13 = TL(csa[i+13]), x14 = TL(csa[i+14]), x15 = TL(csa[i+15]);
        a0 = pk32(a0, x0);  a1 = pk32(a1, x1);  a2 = pk32(a2, x2);  a3 = pk32(a3, x3);
        a0 = pk32(a0, x4);  a1 = pk32(a1, x5);  a2 = pk32(a2, x6);  a3 = pk32(a3, x7);
        a0 = pk32(a0, x8);  a1 = pk32(a1, x9);  a2 = pk32(a2, x10); a3 = pk32(a3, x11);
        a0 = pk32(a0, x12); a1 = pk32(a1, x13); a2 = pk32(a2, x14); a3 = pk32(a3, x15);
      }
      if (i < dpb) {
        uint32_t y0  = TL(csb[i+0]),  y1  = TL(csb[i+1]),  y2  = TL(csb[i+2]),  y3  = TL(csb[i+3]);
        uint32_t y4  = TL(csb[i+4]),  y5  = TL(csb[i+5]),  y6  = TL(csb[i+6]),  y7  = TL(csb[i+7]);
        uint32_t y8  = TL(csb[i+8]),  y9  = TL(csb[i+9]),  y10 = TL(csb[i+10]), y11 = TL(csb[i+11]);
        uint32_t y12 = TL(csb[i+12]), y13 = TL(csb[i+13]), y14 = TL(csb[i+14]), y15 = TL(csb[i+15]);
        b0 = pk32(b0, y0);  b1 = pk32(b1, y1);  b2 = pk32(b2, y2);  b3 = pk32(b3, y3);
        b0 = pk32(b0, y4);  b1 = pk32(b1, y5);  b2 = pk32(b2, y6);  b3 = pk32(b3, y7);
        b0 = pk32(b0, y8);  b1 = pk32(b1, y9);  b2 = pk32(b2, y10); b3 = pk32(b3, y11);
        b0 = pk32(b0, y12); b1 = pk32(b1, y13); b2 = pk32(b2, y14); b3 = pk32(b3, y15);
      }
    }
#undef TL
    uint32_t am = pk32(pk32(a0, a1), pk32(a2, a3));
    uint32_t bm = pk32(pk32(b0, b1), pk32(b2, b3));

    float ua0 = hva.x + b2f((unsigned short)(am & 0xffffu));
    float ua1 = hva.y + b2f((unsigned short)(am >> 16));
    float ub0 = hvb.x + b2f((unsigned short)(bm & 0xffffu));
    float ub1 = hvb.y + b2f((unsigned short)(bm >> 16));
    float ssa = ua0 * ua0 + ua1 * ua1;
    float ssb = ub0 * ub0 + ub1 * ub1;
#pragma unroll
    for (int off = 32; off; off >>= 1) {
      ssa += __shfl_xor(ssa, off);
      ssb += __shfl_xor(ssb, off);
    }
    float rfa = rsqrtf(ssa * (1.f / D) + EPSV);
    float rfb = rsqrtf(ssb * (1.f / D) + EPSV);
    u[nla][d0]         = ua0 * rfa * gc2.x + bgc2.x;
    u[nla][d0 + 1]     = ua1 * rfa * gc2.y + bgc2.y;
    u[nla + 1][d0]     = ub0 * rfb * gc2.x + bgc2.x;
    u[nla + 1][d0 + 1] = ub1 * rfb * gc2.y + bgc2.y;
  }
  __syncthreads();

  // ---- phase 2: MLP GEMM, wave handles ct-tile = wave ----
  const char* whB = (const char*)Whb;
  uint32_t wrow = (uint32_t)(wave * 16 + q) * (D * 2);
  s16x8 a[4];
#pragma unroll
  for (int ks = 0; ks < 4; ++ks) {
    int k0 = ks * 32 + g * 8;
    f32x4 x0 = *(const f32x4*)&u[q][k0];
    f32x4 x1 = *(const f32x4*)&u[q][k0 + 4];
    u16x8 av;
    av[0] = f2b_bits(x0[0]); av[1] = f2b_bits(x0[1]);
    av[2] = f2b_bits(x0[2]); av[3] = f2b_bits(x0[3]);
    av[4] = f2b_bits(x1[0]); av[5] = f2b_bits(x1[1]);
    av[6] = f2b_bits(x1[2]); av[7] = f2b_bits(x1[3]);
    a[ks] = __builtin_bit_cast(s16x8, av);
  }
  f32x4 acc = {0.f, 0.f, 0.f, 0.f};
#pragma unroll
  for (int ks = 0; ks < 4; ++ks) {
    s16x8 b = *(const s16x8*)(whB + wrow + (uint32_t)(ks * 32 + g * 8) * 2);
    acc = __builtin_amdgcn_mfma_f32_16x16x32_bf16(a[ks], b, acc, 0, 0, 0);
  }
  __syncthreads();                         // all A-frag reads done
  {
    int col = wave * 16 + q;
    float bv = bhv[col];
#pragma unroll
    for (int r = 0; r < 4; ++r)
      u[g * 4 + r][col] += fmaxf(acc[r] + bv, 0.f);
  }
  __syncthreads();
  // rmsnorm: wave handles rows {2*wave, 2*wave+1}; write h2 to global + LDS
  {
    int d0 = lane * 2;
    float2 gh2  = *(const float2*)(ghv + d0);
    float2 bgh2 = *(const float2*)(bghv + d0);
#pragma unroll
    for (int j = 0; j < 2; ++j) {
      int r = wave * 2 + j;
      float u0 = u[r][d0], u1 = u[r][d0 + 1];
      float ss = u0 * u0 + u1 * u1;
#pragma unroll
      for (int off2 = 32; off2; off2 >>= 1) ss += __shfl_xor(ss, off2);
      float rf = rsqrtf(ss * (1.f / D) + EPSV);
      float o0 = u0 * rf * gh2.x + bgh2.x;
      float o1 = u1 * rf * gh2.y + bgh2.y;
      u[r][d0]     = o0;
      u[r][d0 + 1] = o1;
      float2 o; o.x = o0; o.y = o1;
      *(float2*)(hout + (size_t)(rowbase + r) * D + d0) = o;
    }
  }

  if (WRITE_T) {
    __syncthreads();
    // phase 3: next-layer edge GEMM from LDS h2
    const char* wcB = (const char*)Wcb;
    s16x8 a2[4];
#pragma unroll
    for (int ks = 0; ks < 4; ++ks) {
      int k0 = ks * 32 + g * 8;
      f32x4 x0 = *(const f32x4*)&u[q][k0];
      f32x4 x1 = *(const f32x4*)&u[q][k0 + 4];
      u16x8 av;
      av[0] = f2b_bits(x0[0]); av[1] = f2b_bits(x0[1]);
      av[2] = f2b_bits(x0[2]); av[3] = f2b_bits(x0[3]);
      av[4] = f2b_bits(x1[0]); av[5] = f2b_bits(x1[1]);
      av[6] = f2b_bits(x1[2]); av[7] = f2b_bits(x1[3]);
      a2[ks] = __builtin_bit_cast(s16x8, av);
    }
    f32x4 acc2 = {0.f, 0.f, 0.f, 0.f};
#pragma unroll
    for (int ks = 0; ks < 4; ++ks) {
      s16x8 b = *(const s16x8*)(wcB + wrow + (uint32_t)(ks * 32 + g * 8) * 2);
      acc2 = __builtin_amdgcn_mfma_f32_16x16x32_bf16(a2[ks], b, acc2, 0, 0, 0);
    }
    __syncthreads();
    {
      int col = wave * 16 + q;
      float bv = bcv[col];
#pragma unroll
      for (int r = 0; r < 4; ++r)
        u[g * 4 + r][col] = fmaxf(acc2[r] + bv, 0.f);
    }
    __syncthreads();
    // coalesced bf16 store: thread -> row tid>>5, cols (tid&31)*4..+3
    {
      int r = tid >> 5, c = (tid & 31) * 4;
      f32x4 v = *(const f32x4*)&u[r][c];
      u16x4 ov;
      ov[0] = f2b_bits(v[0]); ov[1] = f2b_bits(v[1]);
      ov[2] = f2b_bits(v[2]); ov[3] = f2b_bits(v[3]);
      *(u16x4*)(tout + (size_t)(rowbase + r) * D + c) = ov;
    }
  }
}

// ---------------- launch ----------------
extern "C" void kernel_launch(void* const* d_in, const int* in_sizes, int n_in,
                              void* d_out, int out_size, void* d_ws, size_t ws_size,
                              hipStream_t stream) {
  (void)in_sizes; (void)n_in; (void)out_size; (void)ws_size;
  const float* x   = (const float*)d_in[0];
  const int*   e   = (const int*)d_in[1];
  const float* Wc  = (const float*)d_in[2];
  const float* bc  = (const float*)d_in[3];
  const float* gc  = (const float*)d_in[4];
  const float* bgc = (const float*)d_in[5];
  const float* Wh  = (const float*)d_in[6];
  const float* bh  = (const float*)d_in[7];
  const float* gh  = (const float*)d_in[8];
  const float* bgh = (const float*)d_in[9];
  float* out = (float*)d_out;

  // t buffers have NN+1 rows: row NN is the zero sentinel for csr pads
  char* base = (char*)d_ws;
  unsigned short* t0  = (unsigned short*)(base + 0);          // 10,240,256 (+pad)
  unsigned short* t1  = (unsigned short*)(base + 10240512);   // 10,240,256 (+pad)
  float*          hA  = (float*)(base + 20481024);            // 20,480,000
  unsigned short* wcb = (unsigned short*)(base + 40961024);   //    131,072
  unsigned short* whb = (unsigned short*)(base + 41092096);   //    131,072
  int*            deg = (int*)(base + 41223168);              //    160,000
  int*            cur = (int*)(base + 41383168);              //    160,000
  int*            tot = (int*)(base + 41543168);              //         64
  int*            rs  = (int*)(base + 41543232);              //    160,000
  int*            csr = (int*)(base + 41703232);              //  5,120,000

  hipMemsetAsync(deg, 0, 2 * 160000 + 64, stream);   // deg | cur | tot (before k_prep!)
  k_prep<<<5000, 256, 0, stream>>>(Wc, Wh, wcb, whb, csr,
                                   t0 + (size_t)NN * D, t1 + (size_t)NN * D, e, deg);
  k_alloc<<<157, 256, 0, stream>>>(deg, tot, rs);
  k_fill<<<2500, 256, 0, stream>>>(e, rs, cur, csr);

  // layer-0 t on x
  k_gemm0<<<625, 256, 0, stream>>>(x, wcb, bc, t0);

  unsigned short* tbuf[2] = {t0, t1};
  for (int l = 0; l < NL; ++l) {
    const float* hin = (l == 0) ? x : hA;
    const uint32_t* tin = (const uint32_t*)tbuf[l & 1];
    if (l < NL - 1) {
      k_layer<1><<<2500, 512, 0, stream>>>(
          hin, tin, rs, deg, csr,
          gc + l * D, bgc + l * D,
          whb + (size_t)l * D * D, bh + l * D, gh + l * D, bgh + l * D,
          wcb + (size_t)(l + 1) * D * D, bc + (l + 1) * D,
          hA, tbuf[(l + 1) & 1]);
    } else {
      k_layer<0><<<2500, 512, 0, stream>>>(
          hin, tin, rs, deg, csr,
          gc + l * D, bgc + l * D,
          whb + (size_t)l * D * D, bh + l * D, gh + l * D, bgh + l * D,
          nullptr, nullptr,
          out, nullptr);
    }
  }
}